// Round 6
// baseline (19.892 us; speedup 1.0000x reference)
//
#include <hip/hip_runtime.h>
#include <math.h>

#define N_PTS 131072
#define UNITS 256
#define PAIRS (UNITS / 2)
#define BLOCK 256
#define PTS_PER_THREAD 2
#define GRID  (N_PTS / (BLOCK * PTS_PER_THREAD))   // 256 blocks, 2 points/thread

typedef float f32x2 __attribute__((ext_vector_type(2)));

#if defined(__has_builtin)
#  if __has_builtin(__builtin_elementwise_fma)
#    define PK_FMA(a, b, c) __builtin_elementwise_fma((a), (b), (c))
#  endif
#endif
#ifndef PK_FMA
static __device__ __forceinline__ f32x2 pk_fma_fallback(f32x2 a, f32x2 b, f32x2 c) {
    f32x2 r; r.x = fmaf(a.x, b.x, c.x); r.y = fmaf(a.y, b.y, c.y); return r;
}
#  define PK_FMA(a, b, c) pk_fma_fallback((a), (b), (c))
#endif

// Closed form: phi = exp(-0.5*s), s = (x-cx)^2 + (y-cy)^2
//   u_pred = sum phi*w ;  sh = u + 2*lap(u) + biharm(u) = sum phi*w*(s^2-6s+5)
// c = -0.5*log2(e): exp(-0.5*s) = E0*exp2(q), E0 = exp2(c*(x^2+y^2)),
//   q = A*x + B*y + D;  A=-2c*cx, B=-2c*cy, D=c*(cx^2+cy^2)
// s = q/c + r0:  s^2-6s+5 = alpha*q^2 + beta*q + gamma
//   alpha = 1/c^2, beta = (2*r0-6)/c, gamma = r0^2-6*r0+5
// 2 centers AND 2 points per iteration: each ds_read_b128 feeds 2 points.

__global__ __launch_bounds__(BLOCK) void rbf_pinn_main(
    const float* __restrict__ x, const float* __restrict__ y,
    const float* __restrict__ u, const float* __restrict__ centers,
    const float* __restrict__ W, const float* __restrict__ eps,
    const float* __restrict__ delta, const float* __restrict__ gam,
    const int* __restrict__ iters, float* __restrict__ partial)
{
    constexpr double LOG2E = 1.4426950408889634073599;
    constexpr float  cF    = (float)(-0.5 * LOG2E);
    constexpr float  alpha = (float)(1.0 / (0.25 * LOG2E * LOG2E));  // 1/c^2
    constexpr float  m2c   = (float)(2.0 / (-0.5 * LOG2E));          // 2/c
    constexpr float  m6c   = (float)(-6.0 / (-0.5 * LOG2E));         // -6/c

    __shared__ float4 s_ab[PAIRS];   // {A_2p, A_2p+1, B_2p, B_2p+1}
    __shared__ float4 s_dw[PAIRS];   // {D_2p, D_2p+1, w_2p, w_2p+1}
    const int t = threadIdx.x;

    if (t < PAIRS) {
        const float cx0 = centers[4 * t + 0];
        const float cy0 = centers[4 * t + 1];
        const float cx1 = centers[4 * t + 2];
        const float cy1 = centers[4 * t + 3];
        s_ab[t] = make_float4(-2.f * cF * cx0, -2.f * cF * cx1,
                              -2.f * cF * cy0, -2.f * cF * cy1);
        s_dw[t] = make_float4(cF * fmaf(cx0, cx0, cy0 * cy0),
                              cF * fmaf(cx1, cx1, cy1 * cy1),
                              W[2 * t + 0], W[2 * t + 1]);
    }
    __syncthreads();

    const int i0 = blockIdx.x * (BLOCK * PTS_PER_THREAD) + t;
    const int i1 = i0 + BLOCK;

    const float xA = x[i0], yA = y[i0], uA = u[i0];
    const float xB = x[i1], yB = y[i1], uB = u[i1];

    const float rA = fmaf(xA, xA, yA * yA);
    const float rB = fmaf(xB, xB, yB * yB);
    const float E0A = __builtin_amdgcn_exp2f(cF * rA);
    const float E0B = __builtin_amdgcn_exp2f(cF * rB);

    const f32x2 al2 = { alpha, alpha };
    const f32x2 xA2 = { xA, xA }, yA2 = { yA, yA };
    const f32x2 xB2 = { xB, xB }, yB2 = { yB, yB };
    const f32x2 beA = { fmaf(m2c, rA, m6c), fmaf(m2c, rA, m6c) };
    const f32x2 beB = { fmaf(m2c, rB, m6c), fmaf(m2c, rB, m6c) };
    const f32x2 gaA = { fmaf(rA, rA - 6.f, 5.f), fmaf(rA, rA - 6.f, 5.f) };
    const f32x2 gaB = { fmaf(rB, rB - 6.f, 5.f), fmaf(rB, rB - 6.f, 5.f) };

    f32x2 upA = { 0.f, 0.f }, shA = { 0.f, 0.f };
    f32x2 upB = { 0.f, 0.f }, shB = { 0.f, 0.f };

    #pragma unroll 4
    for (int p = 0; p < PAIRS; ++p) {
        const float4 ab4 = s_ab[p];               // ds_read_b128 broadcast
        const float4 dw4 = s_dw[p];               // ds_read_b128 broadcast
        const f32x2 A = { ab4.x, ab4.y };
        const f32x2 B = { ab4.z, ab4.w };
        const f32x2 D = { dw4.x, dw4.y };
        const f32x2 w = { dw4.z, dw4.w };

        const f32x2 qA = PK_FMA(A, xA2, PK_FMA(B, yA2, D));
        const f32x2 qB = PK_FMA(A, xB2, PK_FMA(B, yB2, D));
        f32x2 eA, eB;
        eA.x = __builtin_amdgcn_exp2f(qA.x);
        eA.y = __builtin_amdgcn_exp2f(qA.y);
        eB.x = __builtin_amdgcn_exp2f(qB.x);
        eB.y = __builtin_amdgcn_exp2f(qB.y);
        const f32x2 pA = PK_FMA(al2, qA, beA);
        const f32x2 pB = PK_FMA(al2, qB, beB);
        const f32x2 plA = PK_FMA(qA, pA, gaA);
        const f32x2 plB = PK_FMA(qB, pB, gaB);
        const f32x2 ewA = eA * w;
        const f32x2 ewB = eB * w;
        upA += ewA;
        upB += ewB;
        shA = PK_FMA(ewA, plA, shA);
        shB = PK_FMA(ewB, plB, shB);
    }
    const float upAf = (upA.x + upA.y) * E0A;
    const float shAf = (shA.x + shA.y) * E0A;
    const float upBf = (upB.x + upB.y) * E0B;
    const float shBf = (shB.x + shB.y) * E0B;

    const int   it   = iters[0];
    const float epsv = eps[0];
    const float dl   = delta[0];
    const float gm   = gam[0];
    float c2, c3;
    if (it < 10000)      { c2 = 0.0f; c3 = 0.0f; }
    else if (it < 20000) { c2 = 0.3f; c3 = 0.0f; }
    else if (it < 30000) { c2 = 0.7f; c3 = 0.3f; }
    else                 { c2 = 1.0f; c3 = 1.0f; }

    const float uA2 = upAf * upAf;
    const float uB2 = upBf * upBf;
    const float resA = epsv * upAf - c2 * dl * uA2 - c3 * gm * uA2 * upAf - shAf;
    const float resB = epsv * upBf - c2 * dl * uB2 - c3 * gm * uB2 * upBf - shBf;
    const float dA = upAf - uA;
    const float dB = upBf - uB;

    float a0 = fmaf(dA, dA, dB * dB);
    float a1 = fmaf(uA, uA, uB * uB);
    float a2 = fmaf(resA, resA, resB * resB);

    #pragma unroll
    for (int o = 32; o > 0; o >>= 1) {
        a0 += __shfl_down(a0, o);
        a1 += __shfl_down(a1, o);
        a2 += __shfl_down(a2, o);
    }
    __shared__ float s_r[3][BLOCK / 64];
    const int lane = t & 63;
    const int wv   = t >> 6;
    if (lane == 0) { s_r[0][wv] = a0; s_r[1][wv] = a1; s_r[2][wv] = a2; }
    __syncthreads();
    if (t == 0) {
        float r0s = 0.f, r1s = 0.f, r2s = 0.f;
        #pragma unroll
        for (int w2 = 0; w2 < BLOCK / 64; ++w2) {
            r0s += s_r[0][w2]; r1s += s_r[1][w2]; r2s += s_r[2][w2];
        }
        partial[0 * GRID + blockIdx.x] = r0s;
        partial[1 * GRID + blockIdx.x] = r1s;
        partial[2 * GRID + blockIdx.x] = r2s;
    }
}

// Single-wave final reduction: no LDS, no __syncthreads.
__global__ __launch_bounds__(64) void rbf_pinn_final(
    const float* __restrict__ partial, const float* __restrict__ eps,
    const int* __restrict__ iters, float* __restrict__ out)
{
    const int t = threadIdx.x;
    float a0 = 0.f, a1 = 0.f, a2 = 0.f;
    #pragma unroll
    for (int k = t; k < GRID; k += 64) {
        a0 += partial[0 * GRID + k];
        a1 += partial[1 * GRID + k];
        a2 += partial[2 * GRID + k];
    }
    #pragma unroll
    for (int o = 32; o > 0; o >>= 1) {
        a0 += __shfl_down(a0, o);
        a1 += __shfl_down(a1, o);
        a2 += __shfl_down(a2, o);
    }
    if (t == 0) {
        const float loss_u   = a0 / a1;
        const float loss_pde = a2 / (float)N_PTS;
        const int it = iters[0];
        float cw;
        if (it < 10000)      cw = 0.1f;
        else if (it < 20000) cw = 0.3f;
        else if (it < 30000) cw = 0.6f;
        else                 cw = 1.0f;
        const float e  = eps[0];
        const float p0 = fmaxf(0.f, e - 0.8f);
        const float p1 = fmaxf(0.f, 0.2f - e);
        const float eps_bp = p0 * p0 + p1 * p1;
        out[0] = 0.1f * loss_u + cw * loss_pde + 0.01f * eps_bp;
        out[1] = loss_u;
        out[2] = loss_pde;
    }
}

extern "C" void kernel_launch(void* const* d_in, const int* in_sizes, int n_in,
                              void* d_out, int out_size, void* d_ws, size_t ws_size,
                              hipStream_t stream) {
    const float* x       = (const float*)d_in[0];
    const float* y       = (const float*)d_in[1];
    const float* u       = (const float*)d_in[2];
    const float* centers = (const float*)d_in[3];
    const float* W       = (const float*)d_in[4];
    const float* eps     = (const float*)d_in[5];
    const float* delta   = (const float*)d_in[6];
    const float* gam     = (const float*)d_in[7];
    const int*   iters   = (const int*)d_in[8];
    float* out = (float*)d_out;
    float* partial = (float*)d_ws;   // 3 * GRID floats = 3 KB

    rbf_pinn_main<<<GRID, BLOCK, 0, stream>>>(x, y, u, centers, W, eps, delta,
                                              gam, iters, partial);
    rbf_pinn_final<<<1, 64, 0, stream>>>(partial, eps, iters, out);
}